// Round 2
// baseline (202.115 us; speedup 1.0000x reference)
//
#include <hip/hip_runtime.h>
#include <cstdint>
#include <cstddef>

#define NUM_LAYERS 20
#define HID 1024
#define M_TOTAL 8192

typedef __attribute__((ext_vector_type(8))) short bf16x8;
typedef __attribute__((ext_vector_type(4))) float floatx4;

typedef __attribute__((address_space(1))) unsigned int as1_u32;
typedef __attribute__((address_space(3))) unsigned int as3_u32;

__device__ __forceinline__ unsigned short f2bf(float f) {
  union { float f; unsigned int u; } v; v.f = f;
  unsigned int r = v.u + 0x7fffu + ((v.u >> 16) & 1u);  // RNE
  return (unsigned short)(r >> 16);
}

__device__ __forceinline__ float bf2f(unsigned short u) {
  union { unsigned int u; float f; } v; v.u = ((unsigned int)u) << 16;
  return v.f;
}

// async global->LDS, 16B/lane; LDS ptr must be wave-uniform base (HW adds lane*16)
__device__ __forceinline__ void load16_lds(const void* g, void* l) {
  __builtin_amdgcn_global_load_lds(
      reinterpret_cast<as1_u32*>(reinterpret_cast<uintptr_t>(g)),
      reinterpret_cast<as3_u32*>(reinterpret_cast<uintptr_t>(l)),
      16, 0, 0);
}

// ---- Kernel 1: fused prep. Blocks 0..8191: x fp32->bf16. Blocks 8192..9215: w-sum->bf16 ----
__global__ __launch_bounds__(256) void prep_kernel(const float* __restrict__ x,
                                                   const float* __restrict__ w,
                                                   unsigned short* __restrict__ xb,
                                                   unsigned short* __restrict__ wb) {
  const int b = blockIdx.x;
  if (b < 8192) {
    int idx = b * 256 + threadIdx.x;  // 4 floats / thread
    const float4 v = reinterpret_cast<const float4*>(x)[idx];
    ushort4 o;
    o.x = f2bf(v.x); o.y = f2bf(v.y); o.z = f2bf(v.z); o.w = f2bf(v.w);
    reinterpret_cast<ushort4*>(xb)[idx] = o;
  } else {
    int idx = (b - 8192) * 256 + threadIdx.x;
    float4 s = make_float4(0.f, 0.f, 0.f, 0.f);
    const float4* p = reinterpret_cast<const float4*>(w) + idx;
#pragma unroll
    for (int l = 0; l < NUM_LAYERS; ++l) {
      float4 v = p[(size_t)l * (HID * HID / 4)];
      s.x += v.x; s.y += v.y; s.z += v.z; s.w += v.w;
    }
    ushort4 o;
    o.x = f2bf(s.x); o.y = f2bf(s.y); o.z = f2bf(s.z); o.w = f2bf(s.w);
    reinterpret_cast<ushort4*>(wb)[idx] = o;
  }
}

// ---- Kernel 2: GEMM C[M][N] = A[M][K] @ B[N][K]^T (raw, unscaled), bf16 out ----
// 128x64 tile (MxN), 128 threads = 2 waves, each wave 64x64 (4x4 of 16x16x32 MFMA).
// 1024 blocks -> 4 independent blocks/CU (vs 2 with 256-thread 128x128 tiles):
// more independent barrier groups per CU to hide the global_load_lds drain.
__global__ __launch_bounds__(128, 2) void gemm_kernel(const unsigned short* __restrict__ A,
                                                      const unsigned short* __restrict__ B,
                                                      unsigned short* __restrict__ Cb) {
  __shared__ unsigned short lA[128 * 32];  // 8 KiB
  __shared__ unsigned short lB[64 * 32];   // 4 KiB

  const int tid = threadIdx.x;
  const int lane = tid & 63;
  const int w = tid >> 6;      // wave 0..1 -> M halves
  const int quad = lane >> 4;  // 0..3
  const int mrow = lane & 15;

  const int bid = blockIdx.x;
  const int nb = bid & 15;  // 16 N-tiles inner -> consecutive blocks share A tile (L2)
  const int mb = bid >> 4;  // 64 M-tiles

  // staging: thread t loads 8 bf16 (16 B) from row (t>>2), k-offset (t&3)*8
  const int srow = tid >> 2;          // 0..31
  const int skoff = (tid & 3) * 8;
  const unsigned short* gA = A + (size_t)(mb * 128 + srow) * HID + skoff;
  const unsigned short* gB = B + (size_t)(nb * 64 + srow) * HID + skoff;

  // wave-uniform LDS bases (ushort units): one issue = 32 rows = 2048 B = 1024 ushorts;
  // within an issue, wave w owns ushorts [w*512, w*512+512)
  unsigned short* lAw = lA + w * 512;
  unsigned short* lBw = lB + w * 512;

  floatx4 acc[4][4] = {};

  const unsigned short* ra[4];
  const unsigned short* rb[4];
#pragma unroll
  for (int i = 0; i < 4; ++i)
    ra[i] = lA + (w * 64 + i * 16 + mrow) * 32 + quad * 8;  // A rows: wave-half + i*16
#pragma unroll
  for (int j = 0; j < 4; ++j)
    rb[j] = lB + (j * 16 + mrow) * 32 + quad * 8;

  for (int k0 = 0; k0 < HID; k0 += 32) {
    __syncthreads();  // prior iter's ds_reads done before overwrite
    load16_lds(gA,                    lAw);
    load16_lds(gA + (size_t)32 * HID, lAw + 1024);
    load16_lds(gA + (size_t)64 * HID, lAw + 2048);
    load16_lds(gA + (size_t)96 * HID, lAw + 3072);
    load16_lds(gB,                    lBw);
    load16_lds(gB + (size_t)32 * HID, lBw + 1024);
    gA += 32;
    gB += 32;
    __syncthreads();  // staging visible (compiler drains vmcnt before barrier)

    bf16x8 af[4], bfr[4];
#pragma unroll
    for (int i = 0; i < 4; ++i) af[i] = *reinterpret_cast<const bf16x8*>(ra[i]);
#pragma unroll
    for (int j = 0; j < 4; ++j) bfr[j] = *reinterpret_cast<const bf16x8*>(rb[j]);
#pragma unroll
    for (int i = 0; i < 4; ++i)
#pragma unroll
      for (int j = 0; j < 4; ++j)
        acc[i][j] = __builtin_amdgcn_mfma_f32_16x16x32_bf16(af[i], bfr[j], acc[i][j], 0, 0, 0);
  }

  // epilogue: C/D layout col=lane&15, row=quad*4+reg. Store raw dot as bf16.
  const int row_base = mb * 128 + w * 64 + quad * 4;
  const int col_base = nb * 64 + mrow;
#pragma unroll
  for (int i = 0; i < 4; ++i) {
#pragma unroll
    for (int j = 0; j < 4; ++j) {
#pragma unroll
      for (int r = 0; r < 4; ++r) {
        int row = row_base + i * 16 + r;
        Cb[(size_t)row * HID + col_base + j * 16] = f2bf(acc[i][j][r]);
      }
    }
  }
}

// ---- Kernel 3: RMS norm: out = C * 32 * rsqrt(sum C^2 + 400*eps*H) * norm_w ----
// (C is the raw unscaled dot; /20 folded into the scale-invariant norm, eps term x400)
__global__ __launch_bounds__(256) void rmsnorm_kernel(const unsigned short* __restrict__ Cb,
                                                      const float* __restrict__ nw,
                                                      float* __restrict__ out) {
  const int row = blockIdx.x;
  const int tid = threadIdx.x;
  const ushort4 uv = reinterpret_cast<const ushort4*>(Cb + (size_t)row * HID)[tid];
  float4 v;
  v.x = bf2f(uv.x); v.y = bf2f(uv.y); v.z = bf2f(uv.z); v.w = bf2f(uv.w);
  float ss = v.x * v.x + v.y * v.y + v.z * v.z + v.w * v.w;
#pragma unroll
  for (int off = 32; off > 0; off >>= 1) ss += __shfl_down(ss, off, 64);
  __shared__ float wss[4];
  if ((tid & 63) == 0) wss[tid >> 6] = ss;
  __syncthreads();
  float tot = wss[0] + wss[1] + wss[2] + wss[3];
  float scale = 32.0f * rsqrtf(tot + 0.4096f);  // 32=sqrt(H); 0.4096 = eps*H*400
  float4 w = reinterpret_cast<const float4*>(nw)[tid];
  float4 o;
  o.x = v.x * scale * w.x; o.y = v.y * scale * w.y;
  o.z = v.z * scale * w.z; o.w = v.w * scale * w.w;
  reinterpret_cast<float4*>(out + (size_t)row * HID)[tid] = o;
}

extern "C" void kernel_launch(void* const* d_in, const int* in_sizes, int n_in,
                              void* d_out, int out_size, void* d_ws, size_t ws_size,
                              hipStream_t stream) {
  const float* x = (const float*)d_in[0];       // [2,4096,1024] fp32
  const float* conv_w = (const float*)d_in[1];  // [20,1024,1024] fp32
  const float* norm_w = (const float*)d_in[2];  // [1024] fp32
  float* out = (float*)d_out;                   // [2,4096,1024] fp32

  unsigned short* xb = (unsigned short*)d_ws;       // 16 MiB: A bf16
  unsigned short* wb = xb + (size_t)M_TOTAL * HID;  // +2 MiB: summed W bf16 ([N][K])
  unsigned short* cb = wb + (size_t)HID * HID;      // +16 MiB: C bf16

  prep_kernel<<<8192 + 1024, 256, 0, stream>>>(x, conv_w, xb, wb);
  gemm_kernel<<<(M_TOTAL / 128) * (HID / 64), 128, 0, stream>>>(xb, wb, cb);
  rmsnorm_kernel<<<M_TOTAL, 256, 0, stream>>>(cb, norm_w, out);
}

// Round 3
// 199.436 us; speedup vs baseline: 1.0134x; 1.0134x over previous
//
#include <hip/hip_runtime.h>
#include <cstdint>
#include <cstddef>

#define NUM_LAYERS 20
#define HID 1024
#define M_TOTAL 8192

typedef __attribute__((ext_vector_type(8))) short bf16x8;
typedef __attribute__((ext_vector_type(4))) float floatx4;

typedef __attribute__((address_space(1))) unsigned int as1_u32;
typedef __attribute__((address_space(3))) unsigned int as3_u32;

__device__ __forceinline__ unsigned short f2bf(float f) {
  union { float f; unsigned int u; } v; v.f = f;
  unsigned int r = v.u + 0x7fffu + ((v.u >> 16) & 1u);  // RNE
  return (unsigned short)(r >> 16);
}

__device__ __forceinline__ float bf2f(unsigned short u) {
  union { unsigned int u; float f; } v; v.u = ((unsigned int)u) << 16;
  return v.f;
}

// async global->LDS, 16B/lane; LDS ptr must be wave-uniform base (HW adds lane*16)
__device__ __forceinline__ void load16_lds(const void* g, void* l) {
  __builtin_amdgcn_global_load_lds(
      reinterpret_cast<as1_u32*>(reinterpret_cast<uintptr_t>(g)),
      reinterpret_cast<as3_u32*>(reinterpret_cast<uintptr_t>(l)),
      16, 0, 0);
}

// ---- Kernel 1: fused prep.
// Blocks 0..2047:    x fp32->bf16, 4 float4 per thread (latency hiding via ILP)
// Blocks 2048..3071: conv_w 20-layer sum -> bf16
__global__ __launch_bounds__(256) void prep_kernel(const float* __restrict__ x,
                                                   const float* __restrict__ w,
                                                   unsigned short* __restrict__ xb,
                                                   unsigned short* __restrict__ wb) {
  const int b = blockIdx.x;
  if (b < 2048) {
    const int base = b * 1024 + threadIdx.x;  // float4 index; 4 chunks of 256
    float4 v[4];
#pragma unroll
    for (int j = 0; j < 4; ++j) v[j] = reinterpret_cast<const float4*>(x)[base + j * 256];
#pragma unroll
    for (int j = 0; j < 4; ++j) {
      ushort4 o;
      o.x = f2bf(v[j].x); o.y = f2bf(v[j].y); o.z = f2bf(v[j].z); o.w = f2bf(v[j].w);
      reinterpret_cast<ushort4*>(xb)[base + j * 256] = o;
    }
  } else {
    int idx = (b - 2048) * 256 + threadIdx.x;  // float4 index into [1024,1024]
    float4 s = make_float4(0.f, 0.f, 0.f, 0.f);
    const float4* p = reinterpret_cast<const float4*>(w) + idx;
#pragma unroll
    for (int l = 0; l < NUM_LAYERS; ++l) {
      float4 v = p[(size_t)l * (HID * HID / 4)];
      s.x += v.x; s.y += v.y; s.z += v.z; s.w += v.w;
    }
    ushort4 o;
    o.x = f2bf(s.x); o.y = f2bf(s.y); o.z = f2bf(s.z); o.w = f2bf(s.w);
    reinterpret_cast<ushort4*>(wb)[idx] = o;
  }
}

// ---- Kernel 2: GEMM C[M][N] = A[M][K] @ B[N][K]^T (raw, unscaled), bf16 out ----
// 128x64 tile (MxN), 128 threads = 2 waves, each wave 64x64 (4x4 of 16x16x32 MFMA).
// launch_bounds(128,4): cap VGPR<=128 (est ~120 live) -> more blocks/CU to hide
// the global_load_lds barrier drain.
__global__ __launch_bounds__(128, 4) void gemm_kernel(const unsigned short* __restrict__ A,
                                                      const unsigned short* __restrict__ B,
                                                      unsigned short* __restrict__ Cb) {
  __shared__ unsigned short lA[128 * 32];  // 8 KiB
  __shared__ unsigned short lB[64 * 32];   // 4 KiB

  const int tid = threadIdx.x;
  const int lane = tid & 63;
  const int w = tid >> 6;      // wave 0..1 -> M halves
  const int quad = lane >> 4;  // 0..3
  const int mrow = lane & 15;

  const int bid = blockIdx.x;
  const int nb = bid & 15;  // 16 N-tiles inner -> consecutive blocks share A tile (L2)
  const int mb = bid >> 4;  // 64 M-tiles

  // staging: thread t loads 8 bf16 (16 B) from row (t>>2), k-offset (t&3)*8
  const int srow = tid >> 2;          // 0..31
  const int skoff = (tid & 3) * 8;
  const unsigned short* gA = A + (size_t)(mb * 128 + srow) * HID + skoff;
  const unsigned short* gB = B + (size_t)(nb * 64 + srow) * HID + skoff;

  // wave-uniform LDS bases (ushort units): one issue = 32 rows = 1024 ushorts;
  // within an issue, wave w owns ushorts [w*512, w*512+512)
  unsigned short* lAw = lA + w * 512;
  unsigned short* lBw = lB + w * 512;

  floatx4 acc[4][4] = {};

  const unsigned short* ra[4];
  const unsigned short* rb[4];
#pragma unroll
  for (int i = 0; i < 4; ++i)
    ra[i] = lA + (w * 64 + i * 16 + mrow) * 32 + quad * 8;  // A rows: wave-half + i*16
#pragma unroll
  for (int j = 0; j < 4; ++j)
    rb[j] = lB + (j * 16 + mrow) * 32 + quad * 8;

  for (int k0 = 0; k0 < HID; k0 += 32) {
    __syncthreads();  // prior iter's ds_reads done before overwrite
    load16_lds(gA,                    lAw);
    load16_lds(gA + (size_t)32 * HID, lAw + 1024);
    load16_lds(gA + (size_t)64 * HID, lAw + 2048);
    load16_lds(gA + (size_t)96 * HID, lAw + 3072);
    load16_lds(gB,                    lBw);
    load16_lds(gB + (size_t)32 * HID, lBw + 1024);
    gA += 32;
    gB += 32;
    __syncthreads();  // staging visible (compiler drains vmcnt before barrier)

    bf16x8 af[4], bfr[4];
#pragma unroll
    for (int i = 0; i < 4; ++i) af[i] = *reinterpret_cast<const bf16x8*>(ra[i]);
#pragma unroll
    for (int j = 0; j < 4; ++j) bfr[j] = *reinterpret_cast<const bf16x8*>(rb[j]);
#pragma unroll
    for (int i = 0; i < 4; ++i)
#pragma unroll
      for (int j = 0; j < 4; ++j)
        acc[i][j] = __builtin_amdgcn_mfma_f32_16x16x32_bf16(af[i], bfr[j], acc[i][j], 0, 0, 0);
  }

  // epilogue: C/D layout col=lane&15, row=quad*4+reg. Store raw dot as bf16.
  const int row_base = mb * 128 + w * 64 + quad * 4;
  const int col_base = nb * 64 + mrow;
#pragma unroll
  for (int i = 0; i < 4; ++i) {
#pragma unroll
    for (int j = 0; j < 4; ++j) {
#pragma unroll
      for (int r = 0; r < 4; ++r) {
        int row = row_base + i * 16 + r;
        Cb[(size_t)row * HID + col_base + j * 16] = f2bf(acc[i][j][r]);
      }
    }
  }
}

// ---- Kernel 3: RMS norm, one WAVE per row (no LDS, shuffle-only reduction) ----
// out = C * 32 * rsqrt(sum C^2 + 400*eps*H) * norm_w   (/20 folded into scale)
__global__ __launch_bounds__(256) void rmsnorm_kernel(const unsigned short* __restrict__ Cb,
                                                      const float* __restrict__ nw,
                                                      float* __restrict__ out) {
  const int row = blockIdx.x * 4 + (threadIdx.x >> 6);
  const int lane = threadIdx.x & 63;
  const ushort4* src = reinterpret_cast<const ushort4*>(Cb + (size_t)row * HID);
  float4 v[4];
  float ss = 0.f;
#pragma unroll
  for (int j = 0; j < 4; ++j) {
    ushort4 u = src[lane + j * 64];
    v[j].x = bf2f(u.x); v[j].y = bf2f(u.y); v[j].z = bf2f(u.z); v[j].w = bf2f(u.w);
    ss += v[j].x * v[j].x + v[j].y * v[j].y + v[j].z * v[j].z + v[j].w * v[j].w;
  }
#pragma unroll
  for (int off = 32; off > 0; off >>= 1) ss += __shfl_xor(ss, off, 64);
  const float scale = 32.0f * rsqrtf(ss + 0.4096f);  // 32=sqrt(H); 0.4096 = eps*H*400
  float4* dst = reinterpret_cast<float4*>(out + (size_t)row * HID);
#pragma unroll
  for (int j = 0; j < 4; ++j) {
    float4 wv = reinterpret_cast<const float4*>(nw)[lane + j * 64];
    float4 o;
    o.x = v[j].x * scale * wv.x; o.y = v[j].y * scale * wv.y;
    o.z = v[j].z * scale * wv.z; o.w = v[j].w * scale * wv.w;
    dst[lane + j * 64] = o;
  }
}

extern "C" void kernel_launch(void* const* d_in, const int* in_sizes, int n_in,
                              void* d_out, int out_size, void* d_ws, size_t ws_size,
                              hipStream_t stream) {
  const float* x = (const float*)d_in[0];       // [2,4096,1024] fp32
  const float* conv_w = (const float*)d_in[1];  // [20,1024,1024] fp32
  const float* norm_w = (const float*)d_in[2];  // [1024] fp32
  float* out = (float*)d_out;                   // [2,4096,1024] fp32

  unsigned short* xb = (unsigned short*)d_ws;       // 16 MiB: A bf16
  unsigned short* wb = xb + (size_t)M_TOTAL * HID;  // +2 MiB: summed W bf16 ([N][K])
  unsigned short* cb = wb + (size_t)HID * HID;      // +16 MiB: C bf16

  prep_kernel<<<2048 + 1024, 256, 0, stream>>>(x, conv_w, xb, wb);
  gemm_kernel<<<(M_TOTAL / 128) * (HID / 64), 128, 0, stream>>>(xb, wb, cb);
  rmsnorm_kernel<<<M_TOTAL / 4, 256, 0, stream>>>(cb, norm_w, out);
}

// Round 4
// 193.015 us; speedup vs baseline: 1.0471x; 1.0333x over previous
//
#include <hip/hip_runtime.h>
#include <cstdint>
#include <cstddef>

#define NUM_LAYERS 20
#define HID 1024
#define M_TOTAL 8192

typedef __attribute__((ext_vector_type(8))) short bf16x8;
typedef __attribute__((ext_vector_type(4))) float floatx4;
typedef __attribute__((ext_vector_type(4))) float f32x4;
typedef __attribute__((ext_vector_type(8))) unsigned short u16x8;

typedef __attribute__((address_space(1))) unsigned int as1_u32;
typedef __attribute__((address_space(3))) unsigned int as3_u32;

__device__ __forceinline__ unsigned short f2bf(float f) {
  union { float f; unsigned int u; } v; v.f = f;
  unsigned int r = v.u + 0x7fffu + ((v.u >> 16) & 1u);  // RNE
  return (unsigned short)(r >> 16);
}

__device__ __forceinline__ float bf2f(unsigned short u) {
  union { unsigned int u; float f; } v; v.u = ((unsigned int)u) << 16;
  return v.f;
}

__device__ __forceinline__ u16x8 pack8(f32x4 a, f32x4 b) {
  u16x8 o;
  o[0] = f2bf(a[0]); o[1] = f2bf(a[1]); o[2] = f2bf(a[2]); o[3] = f2bf(a[3]);
  o[4] = f2bf(b[0]); o[5] = f2bf(b[1]); o[6] = f2bf(b[2]); o[7] = f2bf(b[3]);
  return o;
}

// async global->LDS, 16B/lane; LDS ptr must be wave-uniform base (HW adds lane*16)
__device__ __forceinline__ void load16_lds(const void* g, void* l) {
  __builtin_amdgcn_global_load_lds(
      reinterpret_cast<as1_u32*>(reinterpret_cast<uintptr_t>(g)),
      reinterpret_cast<as3_u32*>(reinterpret_cast<uintptr_t>(l)),
      16, 0, 0);
}

// ---- Kernel 1: fused prep, wsum blocks FIRST so their MLP-bound waves overlap
// with the BW-bound xcast waves.
// Blocks 0..511:    conv_w 20-layer sum -> bf16 wb. 40 float4 loads in flight
//                   (the round-3 profile showed 36 VGPRs -> ~4 loads in flight
//                   -> ~1.2 TB/s MLP-bound; this is the fix).
// Blocks 512..2559: x fp32->bf16, 4 float4 loads + 2 ushort8 stores / thread.
__global__ __launch_bounds__(256, 1) void prep_kernel(const float* __restrict__ x,
                                                      const float* __restrict__ w,
                                                      unsigned short* __restrict__ xb,
                                                      unsigned short* __restrict__ wb) {
  const int b = blockIdx.x;
  const int t = threadIdx.x;
  if (b < 512) {
    const int P = b * 256 + t;  // ushort8 output index; float4 pair (2P, 2P+1)
    const f32x4* p = reinterpret_cast<const f32x4*>(w);
    f32x4 va[NUM_LAYERS], vb[NUM_LAYERS];
#pragma unroll
    for (int l = 0; l < NUM_LAYERS; ++l) {
      const f32x4* pl = p + (size_t)l * (HID * HID / 4) + (size_t)2 * P;
      va[l] = __builtin_nontemporal_load(pl);
      vb[l] = __builtin_nontemporal_load(pl + 1);
    }
    f32x4 s0 = va[0], s1 = vb[0];
#pragma unroll
    for (int l = 1; l < NUM_LAYERS; ++l) { s0 += va[l]; s1 += vb[l]; }
    reinterpret_cast<u16x8*>(wb)[P] = pack8(s0, s1);
  } else {
    const int bb = b - 512;
#pragma unroll
    for (int j = 0; j < 2; ++j) {
      const int P = bb * 512 + t + j * 256;  // ushort8 output index
      const f32x4* p = reinterpret_cast<const f32x4*>(x) + (size_t)2 * P;
      f32x4 v0 = __builtin_nontemporal_load(p);
      f32x4 v1 = __builtin_nontemporal_load(p + 1);
      reinterpret_cast<u16x8*>(xb)[P] = pack8(v0, v1);
    }
  }
}

// ---- Kernel 2: GEMM C[M][N] = A[M][K] @ B[N][K]^T (raw, unscaled), bf16 out ----
// 128x64 tile (MxN), 128 threads = 2 waves, each wave 64x64 (4x4 of 16x16x32 MFMA).
__global__ __launch_bounds__(128, 4) void gemm_kernel(const unsigned short* __restrict__ A,
                                                      const unsigned short* __restrict__ B,
                                                      unsigned short* __restrict__ Cb) {
  __shared__ unsigned short lA[128 * 32];  // 8 KiB
  __shared__ unsigned short lB[64 * 32];   // 4 KiB

  const int tid = threadIdx.x;
  const int lane = tid & 63;
  const int w = tid >> 6;      // wave 0..1 -> M halves
  const int quad = lane >> 4;  // 0..3
  const int mrow = lane & 15;

  const int bid = blockIdx.x;
  const int nb = bid & 15;  // 16 N-tiles inner -> consecutive blocks share A tile (L2)
  const int mb = bid >> 4;  // 64 M-tiles

  const int srow = tid >> 2;          // 0..31
  const int skoff = (tid & 3) * 8;
  const unsigned short* gA = A + (size_t)(mb * 128 + srow) * HID + skoff;
  const unsigned short* gB = B + (size_t)(nb * 64 + srow) * HID + skoff;

  unsigned short* lAw = lA + w * 512;
  unsigned short* lBw = lB + w * 512;

  floatx4 acc[4][4] = {};

  const unsigned short* ra[4];
  const unsigned short* rb[4];
#pragma unroll
  for (int i = 0; i < 4; ++i)
    ra[i] = lA + (w * 64 + i * 16 + mrow) * 32 + quad * 8;
#pragma unroll
  for (int j = 0; j < 4; ++j)
    rb[j] = lB + (j * 16 + mrow) * 32 + quad * 8;

  for (int k0 = 0; k0 < HID; k0 += 32) {
    __syncthreads();
    load16_lds(gA,                    lAw);
    load16_lds(gA + (size_t)32 * HID, lAw + 1024);
    load16_lds(gA + (size_t)64 * HID, lAw + 2048);
    load16_lds(gA + (size_t)96 * HID, lAw + 3072);
    load16_lds(gB,                    lBw);
    load16_lds(gB + (size_t)32 * HID, lBw + 1024);
    gA += 32;
    gB += 32;
    __syncthreads();

    bf16x8 af[4], bfr[4];
#pragma unroll
    for (int i = 0; i < 4; ++i) af[i] = *reinterpret_cast<const bf16x8*>(ra[i]);
#pragma unroll
    for (int j = 0; j < 4; ++j) bfr[j] = *reinterpret_cast<const bf16x8*>(rb[j]);
#pragma unroll
    for (int i = 0; i < 4; ++i)
#pragma unroll
      for (int j = 0; j < 4; ++j)
        acc[i][j] = __builtin_amdgcn_mfma_f32_16x16x32_bf16(af[i], bfr[j], acc[i][j], 0, 0, 0);
  }

  // epilogue: C/D layout col=lane&15, row=quad*4+reg. Store raw dot as bf16.
  const int row_base = mb * 128 + w * 64 + quad * 4;
  const int col_base = nb * 64 + mrow;
#pragma unroll
  for (int i = 0; i < 4; ++i) {
#pragma unroll
    for (int j = 0; j < 4; ++j) {
#pragma unroll
      for (int r = 0; r < 4; ++r) {
        int row = row_base + i * 16 + r;
        Cb[(size_t)row * HID + col_base + j * 16] = f2bf(acc[i][j][r]);
      }
    }
  }
}

// ---- Kernel 3: RMS norm, one WAVE per row; ushort8 loads, NT float4 stores ----
// out = C * 32 * rsqrt(sum C^2 + 400*eps*H) * norm_w   (/20 folded into scale)
__global__ __launch_bounds__(256) void rmsnorm_kernel(const unsigned short* __restrict__ Cb,
                                                      const float* __restrict__ nw,
                                                      float* __restrict__ out) {
  const int row = blockIdx.x * 4 + (threadIdx.x >> 6);
  const int lane = threadIdx.x & 63;
  const u16x8* src = reinterpret_cast<const u16x8*>(Cb) + (size_t)row * 128;
  f32x4 v[2][2];
  float ss = 0.f;
#pragma unroll
  for (int j = 0; j < 2; ++j) {
    u16x8 u = src[lane + j * 64];
#pragma unroll
    for (int h = 0; h < 2; ++h) {
#pragma unroll
      for (int e = 0; e < 4; ++e) {
        float f = bf2f(u[h * 4 + e]);
        v[j][h][e] = f;
        ss += f * f;
      }
    }
  }
#pragma unroll
  for (int off = 32; off > 0; off >>= 1) ss += __shfl_xor(ss, off, 64);
  const float scale = 32.0f * rsqrtf(ss + 0.4096f);  // 32=sqrt(H); 0.4096 = eps*H*400
  const f32x4* nwp = reinterpret_cast<const f32x4*>(nw);
  f32x4* dst = reinterpret_cast<f32x4*>(out) + (size_t)row * 256;
#pragma unroll
  for (int j = 0; j < 2; ++j) {
#pragma unroll
    for (int h = 0; h < 2; ++h) {
      const int fi = 2 * (lane + j * 64) + h;
      f32x4 wv = nwp[fi];
      f32x4 o = v[j][h] * scale * wv;
      __builtin_nontemporal_store(o, dst + fi);
    }
  }
}

extern "C" void kernel_launch(void* const* d_in, const int* in_sizes, int n_in,
                              void* d_out, int out_size, void* d_ws, size_t ws_size,
                              hipStream_t stream) {
  const float* x = (const float*)d_in[0];       // [2,4096,1024] fp32
  const float* conv_w = (const float*)d_in[1];  // [20,1024,1024] fp32
  const float* norm_w = (const float*)d_in[2];  // [1024] fp32
  float* out = (float*)d_out;                   // [2,4096,1024] fp32

  unsigned short* xb = (unsigned short*)d_ws;       // 16 MiB: A bf16
  unsigned short* wb = xb + (size_t)M_TOTAL * HID;  // +2 MiB: summed W bf16 ([N][K])
  unsigned short* cb = wb + (size_t)HID * HID;      // +16 MiB: C bf16

  prep_kernel<<<512 + 2048, 256, 0, stream>>>(x, conv_w, xb, wb);
  gemm_kernel<<<(M_TOTAL / 128) * (HID / 64), 128, 0, stream>>>(xb, wb, cb);
  rmsnorm_kernel<<<M_TOTAL / 4, 256, 0, stream>>>(cb, norm_w, out);
}